// Round 3
// baseline (3996.885 us; speedup 1.0000x reference)
//
#include <hip/hip_runtime.h>
#include <cmath>

#define DD 240
#define NHH 8
#define DHH 30
#define DFFF 960
#define NLL 3
#define NPP 4
#define BB 8
#define LEN 5376
#define MTOT (BB*LEN)   // 43008

// ---------------- conv 3x3 SAME + scale/bias + relu, writes (B,LEN,D) layout -------------
// Block: 256 threads = 16x16 pixel tile. blockIdx.y = cout-group of 16 (uniform -> s_load
// weights). blockIdx.x = (b, spatial tile).
template<int CIN, int H, int W>
__global__ __launch_bounds__(256) void conv_bn_relu_kernel(
    const float* __restrict__ in, const float* __restrict__ wgt,
    const float* __restrict__ g, const float* __restrict__ bia,
    float* __restrict__ src, int start)
{
  constexpr int TXN = W / 16;             // tiles per row
  constexpr int TPI = (H / 16) * TXN;     // tiles per image
  const int b  = blockIdx.x / TPI;
  const int tt = blockIdx.x - b * TPI;
  const int y0 = (tt / TXN) * 16;
  const int x0 = (tt - (tt / TXN) * TXN) * 16;
  const int ty = threadIdx.x >> 4, tx = threadIdx.x & 15;
  const int y = y0 + ty, x = x0 + tx;
  const int co0 = blockIdx.y * 16;

  // ci-invariant stencil offsets + masks
  int   off9[9];
  float msk[9];
#pragma unroll
  for (int ky = 0; ky < 3; ++ky) {
#pragma unroll
    for (int kx = 0; kx < 3; ++kx) {
      const int yy = y + ky - 1, xx = x + kx - 1;
      const bool ok = ((unsigned)yy < (unsigned)H) && ((unsigned)xx < (unsigned)W);
      off9[ky*3+kx] = ok ? (yy * W + xx) : 0;
      msk[ky*3+kx]  = ok ? 1.f : 0.f;
    }
  }

  float acc[16];
#pragma unroll
  for (int j = 0; j < 16; ++j) acc[j] = 0.f;

  const float* inb = in + (size_t)b * CIN * H * W;
  const float* wp0 = wgt + (size_t)co0 * CIN * 9;

  for (int ci = 0; ci < CIN; ++ci) {
    const float* inc = inb + (size_t)ci * H * W;
    float v[9];
#pragma unroll
    for (int t9 = 0; t9 < 9; ++t9) v[t9] = inc[off9[t9]] * msk[t9];
#pragma unroll
    for (int j = 0; j < 16; ++j) {
      const float* wp = wp0 + ((size_t)j * CIN + ci) * 9;   // block-uniform -> s_load
#pragma unroll
      for (int t9 = 0; t9 < 9; ++t9) acc[j] = fmaf(v[t9], wp[t9], acc[j]);
    }
  }

  float* srow = src + ((size_t)b * LEN + start + y * W + x) * DD + co0;
#pragma unroll
  for (int q4 = 0; q4 < 4; ++q4) {
    float4 r;
    r.x = fmaxf(fmaf(acc[q4*4+0], g[co0+q4*4+0], bia[co0+q4*4+0]), 0.f);
    r.y = fmaxf(fmaf(acc[q4*4+1], g[co0+q4*4+1], bia[co0+q4*4+1]), 0.f);
    r.z = fmaxf(fmaf(acc[q4*4+2], g[co0+q4*4+2], bia[co0+q4*4+2]), 0.f);
    r.w = fmaxf(fmaf(acc[q4*4+3], g[co0+q4*4+3], bia[co0+q4*4+3]), 0.f);
    *reinterpret_cast<float4*>(srow + q4*4) = r;
  }
}

// ---------------- positional sine embedding + level embed: pos[LEN][240] ----------------
__global__ void pos_kernel(const float* __restrict__ level_embed, float* __restrict__ pos)
{
  const int i = blockIdx.x;        // 0..5375
  const int d = threadIdx.x;       // 0..255
  if (d >= DD) return;
  int l, Hq, Wq, p;
  if (i < 4096)      { l = 0; Hq = 64; Wq = 64; p = i; }
  else if (i < 5120) { l = 1; Hq = 32; Wq = 32; p = i - 4096; }
  else               { l = 2; Hq = 16; Wq = 16; p = i - 5120; }
  const int y = p / Wq, x = p % Wq;
  const int j = d % 120;
  const float coord = (d < 120) ? (float)y : (float)x;
  const float dim   = (d < 120) ? (float)Hq : (float)Wq;
  const float v = (coord + 1.0f) / (dim + 1e-6f) * 6.28318530717958647692f;
  const int k = j >> 1;
  const float t = powf(10000.0f, (float)k / 60.0f);
  const float ang = v / t;
  const float val = (j & 1) ? cosf(ang) : sinf(ang);
  pos[(size_t)i * DD + d] = val + level_embed[l * DD + d];
}

// ---------------- generic fp32 GEMM: C = (A+P?)(MxK) @ W(KxN) + bias (+R) (opt relu) ----
// 128x128 tile, 256 threads, 8x8 per thread as 2x2 clusters of 4x4 (float4 granules).
// P (optional) is a LEN x K matrix added to A rows (row m uses P row m % LEN).
// M % 128 == 0, K % 16 == 0 guaranteed by call sites; N guarded (zero-filled).
#define BM 128
#define BN 128
#define BK 16
__global__ __launch_bounds__(256) void gemm_kernel(
    const float* __restrict__ A, const float* __restrict__ P,
    const float* __restrict__ Wt,
    const float* __restrict__ bias, const float* __restrict__ R,
    float* __restrict__ C, int M, int N, int K, int do_relu)
{
  __shared__ float As[BK][BM + 4];
  __shared__ float Ws[BK][BN + 4];
  const int t  = threadIdx.x;
  const int n0 = blockIdx.x * BN;
  const int m0 = blockIdx.y * BM;
  const int tm = t >> 4;            // 0..15 (m micro-group)
  const int tn = t & 15;            // 0..15 (n micro-group)
  // A staging: row = t>>1 (0..127), k-half = (t&1)*8
  const int ar = t >> 1;
  const int ak = (t & 1) * 8;
  const int prow = (m0 + ar) % LEN; // pos row (only used when P)
  // W staging: row wk = t>>4 (0..15), two col-clusters (t&15)*4 and 64+(t&15)*4
  const int wk = t >> 4;
  const int wn = (t & 15) * 4;

  float acc[2][2][4][4];
#pragma unroll
  for (int mc = 0; mc < 2; ++mc)
#pragma unroll
    for (int nc = 0; nc < 2; ++nc)
#pragma unroll
      for (int i = 0; i < 4; ++i)
#pragma unroll
        for (int j = 0; j < 4; ++j) acc[mc][nc][i][j] = 0.f;

  for (int k0 = 0; k0 < K; k0 += BK) {
    // stage A (two float4 per thread), optionally + pos
    float4 a0 = *reinterpret_cast<const float4*>(&A[(size_t)(m0 + ar) * K + k0 + ak]);
    float4 a1 = *reinterpret_cast<const float4*>(&A[(size_t)(m0 + ar) * K + k0 + ak + 4]);
    if (P) {
      const float4 p0 = *reinterpret_cast<const float4*>(&P[(size_t)prow * K + k0 + ak]);
      const float4 p1 = *reinterpret_cast<const float4*>(&P[(size_t)prow * K + k0 + ak + 4]);
      a0.x += p0.x; a0.y += p0.y; a0.z += p0.z; a0.w += p0.w;
      a1.x += p1.x; a1.y += p1.y; a1.z += p1.z; a1.w += p1.w;
    }
    As[ak + 0][ar] = a0.x; As[ak + 1][ar] = a0.y; As[ak + 2][ar] = a0.z; As[ak + 3][ar] = a0.w;
    As[ak + 4][ar] = a1.x; As[ak + 5][ar] = a1.y; As[ak + 6][ar] = a1.z; As[ak + 7][ar] = a1.w;
    // stage W (two col-clusters per thread, zero-fill OOB cols)
#pragma unroll
    for (int cc = 0; cc < 2; ++cc) {
      const int nb = wn + cc * 64;
      const size_t gro = (size_t)(k0 + wk) * N + n0;
      if (n0 + nb + 3 < N) {
        const float4 wv = *reinterpret_cast<const float4*>(&Wt[gro + nb]);
        Ws[wk][nb + 0] = wv.x; Ws[wk][nb + 1] = wv.y; Ws[wk][nb + 2] = wv.z; Ws[wk][nb + 3] = wv.w;
      } else {
#pragma unroll
        for (int i = 0; i < 4; ++i)
          Ws[wk][nb + i] = (n0 + nb + i < N) ? Wt[gro + nb + i] : 0.f;
      }
    }
    __syncthreads();
#pragma unroll
    for (int k = 0; k < BK; ++k) {
      float a[8], b[8];
      const float4 av0 = *reinterpret_cast<const float4*>(&As[k][tm * 4]);
      const float4 av1 = *reinterpret_cast<const float4*>(&As[k][64 + tm * 4]);
      const float4 bv0 = *reinterpret_cast<const float4*>(&Ws[k][tn * 4]);
      const float4 bv1 = *reinterpret_cast<const float4*>(&Ws[k][64 + tn * 4]);
      a[0]=av0.x; a[1]=av0.y; a[2]=av0.z; a[3]=av0.w;
      a[4]=av1.x; a[5]=av1.y; a[6]=av1.z; a[7]=av1.w;
      b[0]=bv0.x; b[1]=bv0.y; b[2]=bv0.z; b[3]=bv0.w;
      b[4]=bv1.x; b[5]=bv1.y; b[6]=bv1.z; b[7]=bv1.w;
#pragma unroll
      for (int mc = 0; mc < 2; ++mc)
#pragma unroll
        for (int i = 0; i < 4; ++i)
#pragma unroll
          for (int nc = 0; nc < 2; ++nc)
#pragma unroll
            for (int j = 0; j < 4; ++j)
              acc[mc][nc][i][j] = fmaf(a[mc*4+i], b[nc*4+j], acc[mc][nc][i][j]);
    }
    __syncthreads();
  }

#pragma unroll
  for (int mc = 0; mc < 2; ++mc) {
#pragma unroll
    for (int i = 0; i < 4; ++i) {
      const int m = m0 + mc * 64 + tm * 4 + i;
#pragma unroll
      for (int nc = 0; nc < 2; ++nc) {
        const int nb = n0 + nc * 64 + tn * 4;
        if (nb < N) {   // N % 4 == 0 at all call sites -> whole float4 valid
          const float4 bb = *reinterpret_cast<const float4*>(&bias[nb]);
          float4 c;
          c.x = acc[mc][nc][i][0] + bb.x;
          c.y = acc[mc][nc][i][1] + bb.y;
          c.z = acc[mc][nc][i][2] + bb.z;
          c.w = acc[mc][nc][i][3] + bb.w;
          if (R) {
            const float4 rr = *reinterpret_cast<const float4*>(&R[(size_t)m * N + nb]);
            c.x += rr.x; c.y += rr.y; c.z += rr.z; c.w += rr.w;
          }
          if (do_relu) {
            c.x = fmaxf(c.x, 0.f); c.y = fmaxf(c.y, 0.f);
            c.z = fmaxf(c.z, 0.f); c.w = fmaxf(c.w, 0.f);
          }
          *reinterpret_cast<float4*>(&C[(size_t)m * N + nb]) = c;
        }
      }
    }
  }
}

// ---------------- softmax over 12 (per b,i,h), in place ----------------
__global__ void softmax12_kernel(float* __restrict__ aw)
{
  const size_t t = (size_t)blockIdx.x * blockDim.x + threadIdx.x;
  if (t >= (size_t)MTOT * NHH) return;
  float* p = aw + t * 12;
  float v[12];
  float m = -1e30f;
#pragma unroll
  for (int j = 0; j < 12; ++j) { v[j] = p[j]; m = fmaxf(m, v[j]); }
  float s = 0.f;
#pragma unroll
  for (int j = 0; j < 12; ++j) { v[j] = expf(v[j] - m); s += v[j]; }
  const float inv = 1.0f / s;
#pragma unroll
  for (int j = 0; j < 12; ++j) p[j] = v[j] * inv;
}

// ---------------- multi-scale deformable sampling + attention-weighted sum -------------
__global__ __launch_bounds__(256) void msdeform_kernel(
    const float* __restrict__ value, const float* __restrict__ off,
    const float* __restrict__ aw, float* __restrict__ samp)
{
  const int grp = threadIdx.x >> 5;    // 0..7 : (b,i,h) tuple within block
  const int d   = threadIdx.x & 31;    // channel lane (d<30 active)
  const size_t idx = (size_t)blockIdx.x * 8 + grp;     // (b*LEN+i)*NH + h
  const int h = (int)(idx % NHH);
  const size_t bi = idx / NHH;
  const int i = (int)(bi % LEN);
  const int b = (int)(bi / LEN);

  int Hq, Wq, p;
  if (i < 4096)      { Hq = 64; Wq = 64; p = i; }
  else if (i < 5120) { Hq = 32; Wq = 32; p = i - 4096; }
  else               { Hq = 16; Wq = 16; p = i - 5120; }
  const float rx = ((p % Wq) + 0.5f) / (float)Wq;
  const float ry = ((p / Wq) + 0.5f) / (float)Hq;

  const float* offp = off + idx * (NLL * NPP * 2);
  const float* awp  = aw  + idx * 12;

  const int Ls[3] = {0, 4096, 5120};
  const int Hs[3] = {64, 32, 16};
  float acc = 0.f;
#pragma unroll
  for (int l = 0; l < 3; ++l) {
    const int Wl = Hs[l], Hl = Hs[l];
    const int st = Ls[l];
#pragma unroll
    for (int pp = 0; pp < 4; ++pp) {
      const float ox = offp[(l*4 + pp)*2 + 0];
      const float oy = offp[(l*4 + pp)*2 + 1];
      const float a  = awp[l*4 + pp];
      const float gx = rx * Wl + ox - 0.5f;
      const float gy = ry * Hl + oy - 0.5f;
      const float x0 = floorf(gx), y0 = floorf(gy);
      const float wx = gx - x0, wy = gy - y0;
      const int ix = (int)x0, iy = (int)y0;
#pragma unroll
      for (int c = 0; c < 4; ++c) {
        const int cx = ix + (c & 1), cy = iy + (c >> 1);
        const float wgt = ((c & 1) ? wx : 1.f - wx) * ((c >> 1) ? wy : 1.f - wy);
        if (cx >= 0 && cx < Wl && cy >= 0 && cy < Hl && d < DHH) {
          const float vv = value[(((size_t)b * LEN + st + cy*Wl + cx) * NHH + h) * DHH + d];
          acc = fmaf(a * wgt, vv, acc);
        }
      }
    }
  }
  if (d < DHH)
    samp[((size_t)b * LEN + i) * DD + h * DHH + d] = acc;
}

// ---------------- out = LN(X (+Y)) rowwise over 240 ----------------
__global__ __launch_bounds__(256) void add_ln_kernel(
    const float* __restrict__ X, const float* __restrict__ Y,
    const float* __restrict__ g, const float* __restrict__ bet,
    float* __restrict__ out)
{
  const int lane = threadIdx.x & 63;
  const int row  = blockIdx.x * 4 + (threadIdx.x >> 6);
  float4 v = make_float4(0.f, 0.f, 0.f, 0.f);
  if (lane < 60) {
    v = *reinterpret_cast<const float4*>(X + (size_t)row * DD + lane*4);
    if (Y) {
      const float4 w = *reinterpret_cast<const float4*>(Y + (size_t)row * DD + lane*4);
      v.x += w.x; v.y += w.y; v.z += w.z; v.w += w.w;
    }
  }
  float s = v.x + v.y + v.z + v.w;
#pragma unroll
  for (int o = 32; o > 0; o >>= 1) s += __shfl_xor(s, o, 64);
  const float mean = s * (1.0f / 240.0f);
  float sq = 0.f;
  if (lane < 60) {
    const float a = v.x - mean, b2 = v.y - mean, c = v.z - mean, e = v.w - mean;
    sq = a*a + b2*b2 + c*c + e*e;
  }
#pragma unroll
  for (int o = 32; o > 0; o >>= 1) sq += __shfl_xor(sq, o, 64);
  const float var = sq * (1.0f / 240.0f);
  const float rs = rsqrtf(var + 1e-5f);
  if (lane < 60) {
    const float4 gg = *reinterpret_cast<const float4*>(g + lane*4);
    const float4 bb = *reinterpret_cast<const float4*>(bet + lane*4);
    float* orow = out + (size_t)row * DD + lane*4;
    orow[0] = (v.x - mean) * rs * gg.x + bb.x;
    orow[1] = (v.y - mean) * rs * gg.y + bb.y;
    orow[2] = (v.z - mean) * rs * gg.z + bb.z;
    orow[3] = (v.w - mean) * rs * gg.w + bb.w;
  }
}

// ---------------- scatter (B,LEN,240) -> (B,240,H,W) with LDS transpose ----------------
template<int HW>
__global__ void scatter_kernel(const float* __restrict__ src2, float* __restrict__ out,
                               int start, size_t out_off)
{
  __shared__ float tile[32][33];
  const int tx = threadIdx.x;   // 32
  const int ty = threadIdx.y;   // 8
#pragma unroll
  for (int r = 0; r < 4; ++r) {
    const int prow = ty + 8*r;
    const int gp = blockIdx.x * 32 + prow;
    const int b = gp / HW, pix = gp % HW;
    const int co = blockIdx.y * 32 + tx;
    if (co < DD)
      tile[prow][tx] = src2[((size_t)b * LEN + start + pix) * DD + co];
  }
  __syncthreads();
#pragma unroll
  for (int r = 0; r < 4; ++r) {
    const int crow = ty + 8*r;
    const int co = blockIdx.y * 32 + crow;
    if (co < DD) {
      const int gp = blockIdx.x * 32 + tx;
      const int b = gp / HW, pix = gp % HW;
      out[out_off + ((size_t)b * DD + co) * HW + pix] = tile[tx][crow];
    }
  }
}

extern "C" void kernel_launch(void* const* d_in, const int* in_sizes, int n_in,
                              void* d_out, int out_size, void* d_ws, size_t ws_size,
                              hipStream_t stream)
{
  (void)in_sizes; (void)n_in; (void)out_size; (void)ws_size;
  const float* x0  = (const float*)d_in[0];
  const float* x1  = (const float*)d_in[1];
  const float* x2  = (const float*)d_in[2];
  const float* x3  = (const float*)d_in[3];
  const float* x4  = (const float*)d_in[4];
  const float* p2w = (const float*)d_in[5];
  const float* p2g = (const float*)d_in[6];
  const float* p2b = (const float*)d_in[7];
  const float* p3w = (const float*)d_in[8];
  const float* p3g = (const float*)d_in[9];
  const float* p3b = (const float*)d_in[10];
  const float* p4w = (const float*)d_in[11];
  const float* p4g = (const float*)d_in[12];
  const float* p4b = (const float*)d_in[13];
  const float* lev = (const float*)d_in[14];
  const float* so_w = (const float*)d_in[15];
  const float* so_b = (const float*)d_in[16];
  const float* aw_w = (const float*)d_in[17];
  const float* aw_b = (const float*)d_in[18];
  const float* vp_w = (const float*)d_in[19];
  const float* vp_b = (const float*)d_in[20];
  const float* op_w = (const float*)d_in[21];
  const float* op_b = (const float*)d_in[22];
  const float* n1g = (const float*)d_in[23];
  const float* n1b = (const float*)d_in[24];
  const float* f1w = (const float*)d_in[25];
  const float* f1b = (const float*)d_in[26];
  const float* f2w = (const float*)d_in[27];
  const float* f2b = (const float*)d_in[28];
  const float* n2g = (const float*)d_in[29];
  const float* n2b = (const float*)d_in[30];

  float* ws = (float*)d_ws;
  float* src  = ws + 0;               // 10,321,920
  float* offb = ws + 10321920;        //  8,257,536 (later attn)
  float* awb  = ws + 18579456;        //  4,128,768
  float* val  = ws + 22708224;        // 10,321,920 (later f2)
  float* smp  = ws + 33030144;        // 10,321,920 (later mid)
  float* pos  = ws + 43352064;        //  1,290,240
  float* src1 = ws + 44642304;        // 10,321,920   total 54,964,224 floats (~220 MB)
  float* attn = offb;
  float* mid  = smp;
  float* f2   = val;
  float* fin  = src;
  float* outf = (float*)d_out;

  // passthrough copies
  hipMemcpyAsync(outf, x0, (size_t)33554432 * 4, hipMemcpyDeviceToDevice, stream);
  hipMemcpyAsync(outf + 33554432, x1, (size_t)8388608 * 4, hipMemcpyDeviceToDevice, stream);

  // conv + bn + relu into (B,LEN,D) src
  conv_bn_relu_kernel<128,64,64><<<dim3(128, 15), 256, 0, stream>>>(x2, p2w, p2g, p2b, src, 0);
  conv_bn_relu_kernel<256,32,32><<<dim3(32, 15),  256, 0, stream>>>(x3, p3w, p3g, p3b, src, 4096);
  conv_bn_relu_kernel<512,16,16><<<dim3(8, 15),   256, 0, stream>>>(x4, p4w, p4g, p4b, src, 5120);

  pos_kernel<<<LEN, 256, 0, stream>>>(lev, pos);

  // projections (off/aw read src+pos via fused P operand)
  gemm_kernel<<<dim3(2, 336), 256, 0, stream>>>(src, pos, so_w, so_b, nullptr, offb, MTOT, 192, 240, 0);
  gemm_kernel<<<dim3(1, 336), 256, 0, stream>>>(src, pos, aw_w, aw_b, nullptr, awb,  MTOT,  96, 240, 0);
  softmax12_kernel<<<1344, 256, 0, stream>>>(awb);
  gemm_kernel<<<dim3(2, 336), 256, 0, stream>>>(src, nullptr, vp_w, vp_b, nullptr, val, MTOT, 240, 240, 0);

  msdeform_kernel<<<43008, 256, 0, stream>>>(val, offb, awb, smp);

  // output projection + residual LN1
  gemm_kernel<<<dim3(2, 336), 256, 0, stream>>>(smp, nullptr, op_w, op_b, nullptr, attn, MTOT, 240, 240, 0);
  add_ln_kernel<<<10752, 256, 0, stream>>>(src, attn, n1g, n1b, src1);

  // FFN, 4 row-chunks to bound workspace
  for (int c = 0; c < 4; ++c) {
    const float* a = src1 + (size_t)c * 10752 * DD;
    gemm_kernel<<<dim3(8, 84), 256, 0, stream>>>(a,   nullptr, f1w, f1b, nullptr, mid, 10752, 960, 240, 1);
    gemm_kernel<<<dim3(2, 84), 256, 0, stream>>>(mid, nullptr, f2w, f2b, a, f2 + (size_t)c * 10752 * DD,
                                                 10752, 240, 960, 0);
  }
  add_ln_kernel<<<10752, 256, 0, stream>>>(f2, nullptr, n2g, n2b, fin);

  // scatter back to NCHW outputs
  scatter_kernel<4096><<<dim3(1024, 8), dim3(32, 8), 0, stream>>>(fin, outf, 0,    41943040u);
  scatter_kernel<1024><<<dim3(256, 8),  dim3(32, 8), 0, stream>>>(fin, outf, 4096, 49807360u);
  scatter_kernel<256> <<<dim3(64, 8),   dim3(32, 8), 0, stream>>>(fin, outf, 5120, 51773440u);
}

// Round 4
// 2624.600 us; speedup vs baseline: 1.5229x; 1.5229x over previous
//
#include <hip/hip_runtime.h>
#include <cmath>

#define DD 240
#define NHH 8
#define DHH 30
#define DFFF 960
#define NLL 3
#define NPP 4
#define BB 8
#define LEN 5376
#define MTOT (BB*LEN)   // 43008

// ---------------- NCHW -> NHWC transpose (per level) ----------------
template<int C, int HW>
__global__ __launch_bounds__(256) void nchw_to_nhwc_kernel(
    const float* __restrict__ in, float* __restrict__ out)
{
  __shared__ float tile[32][33];
  const int b  = blockIdx.z;
  const int p0 = blockIdx.x * 32;
  const int c0 = blockIdx.y * 32;
  const int tx = threadIdx.x, ty = threadIdx.y;   // 32 x 8
  const float* inb = in + (size_t)b * C * HW;
  float* outb = out + (size_t)b * HW * C;
#pragma unroll
  for (int r = 0; r < 4; ++r)
    tile[ty + 8*r][tx] = inb[(size_t)(c0 + ty + 8*r) * HW + p0 + tx];
  __syncthreads();
#pragma unroll
  for (int r = 0; r < 4; ++r)
    outb[(size_t)(p0 + ty + 8*r) * C + c0 + tx] = tile[tx][ty + 8*r];
}

// ---------------- weight transpose: (240, C*9) -> (9, C, 240), k row = tap*C+ci --------
template<int C>
__global__ __launch_bounds__(256) void wtrans_kernel(
    const float* __restrict__ w, float* __restrict__ wt)
{
  __shared__ float tile[32][33];
  constexpr int K = C * 9;
  const int k0 = blockIdx.x * 32;
  const int o0 = blockIdx.y * 32;
  const int tx = threadIdx.x, ty = threadIdx.y;   // 32 x 8
#pragma unroll
  for (int r = 0; r < 4; ++r) {
    const int o = o0 + ty + 8*r;
    tile[ty + 8*r][tx] = (o < DD) ? w[(size_t)o * K + k0 + tx] : 0.f;
  }
  __syncthreads();
#pragma unroll
  for (int r = 0; r < 4; ++r) {
    const int k = k0 + ty + 8*r;
    const int ci = k / 9, tap = k % 9;
    const int o = o0 + tx;
    if (o < DD) wt[((size_t)tap * C + ci) * DD + o] = tile[tx][ty + 8*r];
  }
}

// ---------------- conv as tap-summed implicit GEMM, BM=128 (level 0), direct epilogue ---
template<int C, int H, int W>
__global__ __launch_bounds__(256) void conv_gemm128_kernel(
    const float* __restrict__ xt, const float* __restrict__ wt,
    const float* __restrict__ g, const float* __restrict__ bia,
    float* __restrict__ src, int start)
{
  constexpr int HW = H * W;
  __shared__ float As[16][128 + 4];
  __shared__ float Ws[16][128 + 4];
  const int t  = threadIdx.x;
  const int n0 = blockIdx.x * 128;
  const int m0 = blockIdx.y * 128;   // 128 | HW -> block within one batch image
  const int tm = t >> 4, tn = t & 15;
  const int ar = t >> 1, ak = (t & 1) * 8;
  const int wk = t >> 4, wn = (t & 15) * 4;
  const int b    = m0 / HW;
  const int pix0 = m0 % HW;
  const int apix = pix0 + ar;
  const int apy = apix / W, apx = apix % W;
  const float* xtb = xt + (size_t)b * HW * C;

  float acc[2][2][4][4];
#pragma unroll
  for (int mc = 0; mc < 2; ++mc)
#pragma unroll
    for (int nc = 0; nc < 2; ++nc)
#pragma unroll
      for (int i = 0; i < 4; ++i)
#pragma unroll
        for (int j = 0; j < 4; ++j) acc[mc][nc][i][j] = 0.f;

  for (int tap = 0; tap < 9; ++tap) {
    const int dy = tap / 3 - 1, dx = tap % 3 - 1;
    const int sy = apy + dy, sx = apx + dx;
    const bool ok = ((unsigned)sy < (unsigned)H) && ((unsigned)sx < (unsigned)W);
    const float* arow = xtb + (size_t)(sy * W + sx) * C;
    const float* wrow = wt + (size_t)tap * C * DD;
    for (int c0 = 0; c0 < C; c0 += 16) {
      float4 a0 = make_float4(0.f,0.f,0.f,0.f), a1 = a0;
      if (ok) {
        a0 = *reinterpret_cast<const float4*>(arow + c0 + ak);
        a1 = *reinterpret_cast<const float4*>(arow + c0 + ak + 4);
      }
      As[ak + 0][ar] = a0.x; As[ak + 1][ar] = a0.y; As[ak + 2][ar] = a0.z; As[ak + 3][ar] = a0.w;
      As[ak + 4][ar] = a1.x; As[ak + 5][ar] = a1.y; As[ak + 6][ar] = a1.z; As[ak + 7][ar] = a1.w;
#pragma unroll
      for (int cc = 0; cc < 2; ++cc) {
        const int nb = wn + cc * 64;
        const size_t gro = (size_t)(c0 + wk) * DD + n0;
        if (n0 + nb + 3 < DD) {
          const float4 wv = *reinterpret_cast<const float4*>(&wrow[gro + nb]);
          Ws[wk][nb+0] = wv.x; Ws[wk][nb+1] = wv.y; Ws[wk][nb+2] = wv.z; Ws[wk][nb+3] = wv.w;
        } else {
#pragma unroll
          for (int i = 0; i < 4; ++i)
            Ws[wk][nb + i] = (n0 + nb + i < DD) ? wrow[gro + nb + i] : 0.f;
        }
      }
      __syncthreads();
#pragma unroll
      for (int k = 0; k < 16; ++k) {
        float a[8], bv[8];
        const float4 av0 = *reinterpret_cast<const float4*>(&As[k][tm * 4]);
        const float4 av1 = *reinterpret_cast<const float4*>(&As[k][64 + tm * 4]);
        const float4 bv0 = *reinterpret_cast<const float4*>(&Ws[k][tn * 4]);
        const float4 bv1 = *reinterpret_cast<const float4*>(&Ws[k][64 + tn * 4]);
        a[0]=av0.x; a[1]=av0.y; a[2]=av0.z; a[3]=av0.w;
        a[4]=av1.x; a[5]=av1.y; a[6]=av1.z; a[7]=av1.w;
        bv[0]=bv0.x; bv[1]=bv0.y; bv[2]=bv0.z; bv[3]=bv0.w;
        bv[4]=bv1.x; bv[5]=bv1.y; bv[6]=bv1.z; bv[7]=bv1.w;
#pragma unroll
        for (int mc = 0; mc < 2; ++mc)
#pragma unroll
          for (int i = 0; i < 4; ++i)
#pragma unroll
            for (int nc = 0; nc < 2; ++nc)
#pragma unroll
              for (int j = 0; j < 4; ++j)
                acc[mc][nc][i][j] = fmaf(a[mc*4+i], bv[nc*4+j], acc[mc][nc][i][j]);
      }
      __syncthreads();
    }
  }

#pragma unroll
  for (int mc = 0; mc < 2; ++mc) {
#pragma unroll
    for (int i = 0; i < 4; ++i) {
      const int pix = pix0 + mc * 64 + tm * 4 + i;
      float* srow = src + ((size_t)b * LEN + start + pix) * DD;
#pragma unroll
      for (int nc = 0; nc < 2; ++nc) {
        const int col = n0 + nc * 64 + tn * 4;
        if (col < DD) {
          float4 c;
          c.x = fmaxf(fmaf(acc[mc][nc][i][0], g[col+0], bia[col+0]), 0.f);
          c.y = fmaxf(fmaf(acc[mc][nc][i][1], g[col+1], bia[col+1]), 0.f);
          c.z = fmaxf(fmaf(acc[mc][nc][i][2], g[col+2], bia[col+2]), 0.f);
          c.w = fmaxf(fmaf(acc[mc][nc][i][3], g[col+3], bia[col+3]), 0.f);
          *reinterpret_cast<float4*>(srow + col) = c;
        }
      }
    }
  }
}

// ---------------- conv implicit GEMM, BM=64, 3-way tap-split-K -> partials -------------
template<int C, int H, int W>
__global__ __launch_bounds__(256) void conv_gemm64s_kernel(
    const float* __restrict__ xt, const float* __restrict__ wt,
    float* __restrict__ part)   // [3][B*HW][240]
{
  constexpr int HW = H * W;
  constexpr int M = BB * HW;
  __shared__ float As[16][64 + 4];
  __shared__ float Ws[16][128 + 4];
  const int t  = threadIdx.x;
  const int z  = blockIdx.z;          // tap group: taps [3z, 3z+3)
  const int n0 = blockIdx.x * 128;
  const int m0 = blockIdx.y * 64;     // 64 | HW
  const int tm = t >> 4, tn = t & 15;
  const int ar = t >> 2, ak = (t & 3) * 4;
  const int wk = t >> 4, wn = (t & 15) * 4;
  const int b    = m0 / HW;
  const int pix0 = m0 % HW;
  const int apix = pix0 + ar;
  const int apy = apix / W, apx = apix % W;
  const float* xtb = xt + (size_t)b * HW * C;

  float acc[4][2][4];
#pragma unroll
  for (int i = 0; i < 4; ++i)
#pragma unroll
    for (int nc = 0; nc < 2; ++nc)
#pragma unroll
      for (int j = 0; j < 4; ++j) acc[i][nc][j] = 0.f;

  for (int tap = 3*z; tap < 3*z + 3; ++tap) {
    const int dy = tap / 3 - 1, dx = tap % 3 - 1;
    const int sy = apy + dy, sx = apx + dx;
    const bool ok = ((unsigned)sy < (unsigned)H) && ((unsigned)sx < (unsigned)W);
    const float* arow = xtb + (size_t)(sy * W + sx) * C;
    const float* wrow = wt + (size_t)tap * C * DD;
    for (int c0 = 0; c0 < C; c0 += 16) {
      float4 a0 = make_float4(0.f,0.f,0.f,0.f);
      if (ok) a0 = *reinterpret_cast<const float4*>(arow + c0 + ak);
      As[ak + 0][ar] = a0.x; As[ak + 1][ar] = a0.y;
      As[ak + 2][ar] = a0.z; As[ak + 3][ar] = a0.w;
#pragma unroll
      for (int cc = 0; cc < 2; ++cc) {
        const int nb = wn + cc * 64;
        const size_t gro = (size_t)(c0 + wk) * DD + n0;
        if (n0 + nb + 3 < DD) {
          const float4 wv = *reinterpret_cast<const float4*>(&wrow[gro + nb]);
          Ws[wk][nb+0] = wv.x; Ws[wk][nb+1] = wv.y; Ws[wk][nb+2] = wv.z; Ws[wk][nb+3] = wv.w;
        } else {
#pragma unroll
          for (int i = 0; i < 4; ++i)
            Ws[wk][nb + i] = (n0 + nb + i < DD) ? wrow[gro + nb + i] : 0.f;
        }
      }
      __syncthreads();
#pragma unroll
      for (int k = 0; k < 16; ++k) {
        float a[4], bv[8];
        const float4 av = *reinterpret_cast<const float4*>(&As[k][tm * 4]);
        const float4 bv0 = *reinterpret_cast<const float4*>(&Ws[k][tn * 4]);
        const float4 bv1 = *reinterpret_cast<const float4*>(&Ws[k][64 + tn * 4]);
        a[0]=av.x; a[1]=av.y; a[2]=av.z; a[3]=av.w;
        bv[0]=bv0.x; bv[1]=bv0.y; bv[2]=bv0.z; bv[3]=bv0.w;
        bv[4]=bv1.x; bv[5]=bv1.y; bv[6]=bv1.z; bv[7]=bv1.w;
#pragma unroll
        for (int i = 0; i < 4; ++i)
#pragma unroll
          for (int nc = 0; nc < 2; ++nc)
#pragma unroll
            for (int j = 0; j < 4; ++j)
              acc[i][nc][j] = fmaf(a[i], bv[nc*4+j], acc[i][nc][j]);
      }
      __syncthreads();
    }
  }

  float* pz = part + (size_t)z * M * DD;
#pragma unroll
  for (int i = 0; i < 4; ++i) {
    const int m = m0 + tm * 4 + i;
#pragma unroll
    for (int nc = 0; nc < 2; ++nc) {
      const int col = n0 + nc * 64 + tn * 4;
      if (col < DD) {
        float4 c;
        c.x = acc[i][nc][0]; c.y = acc[i][nc][1];
        c.z = acc[i][nc][2]; c.w = acc[i][nc][3];
        *reinterpret_cast<float4*>(pz + (size_t)m * DD + col) = c;
      }
    }
  }
}

// ---------------- sum 3 partials + BN + ReLU -> src layout ----------------
template<int HW>
__global__ __launch_bounds__(256) void reduce3_bn_relu_kernel(
    const float* __restrict__ part, const float* __restrict__ g,
    const float* __restrict__ bia, float* __restrict__ src, int start)
{
  constexpr int M = BB * HW;
  const int tid = blockIdx.x * 256 + threadIdx.x;
  if (tid >= M * 60) return;
  const int m = tid / 60, nq = (tid % 60) * 4;
  const size_t ro = (size_t)m * DD + nq;
  const float4 p0 = *reinterpret_cast<const float4*>(part + ro);
  const float4 p1 = *reinterpret_cast<const float4*>(part + (size_t)M * DD + ro);
  const float4 p2 = *reinterpret_cast<const float4*>(part + (size_t)2 * M * DD + ro);
  const float4 gg = *reinterpret_cast<const float4*>(g + nq);
  const float4 bb = *reinterpret_cast<const float4*>(bia + nq);
  float4 c;
  c.x = fmaxf(fmaf(p0.x + p1.x + p2.x, gg.x, bb.x), 0.f);
  c.y = fmaxf(fmaf(p0.y + p1.y + p2.y, gg.y, bb.y), 0.f);
  c.z = fmaxf(fmaf(p0.z + p1.z + p2.z, gg.z, bb.z), 0.f);
  c.w = fmaxf(fmaf(p0.w + p1.w + p2.w, gg.w, bb.w), 0.f);
  const int b = m / HW, pix = m % HW;
  *reinterpret_cast<float4*>(src + ((size_t)b * LEN + start + pix) * DD + nq) = c;
}

// ---------------- positional sine embedding + level embed: pos[LEN][240] ----------------
__global__ void pos_kernel(const float* __restrict__ level_embed, float* __restrict__ pos)
{
  const int i = blockIdx.x;        // 0..5375
  const int d = threadIdx.x;       // 0..255
  if (d >= DD) return;
  int l, Hq, Wq, p;
  if (i < 4096)      { l = 0; Hq = 64; Wq = 64; p = i; }
  else if (i < 5120) { l = 1; Hq = 32; Wq = 32; p = i - 4096; }
  else               { l = 2; Hq = 16; Wq = 16; p = i - 5120; }
  const int y = p / Wq, x = p % Wq;
  const int j = d % 120;
  const float coord = (d < 120) ? (float)y : (float)x;
  const float dim   = (d < 120) ? (float)Hq : (float)Wq;
  const float v = (coord + 1.0f) / (dim + 1e-6f) * 6.28318530717958647692f;
  const int k = j >> 1;
  const float t = powf(10000.0f, (float)k / 60.0f);
  const float ang = v / t;
  const float val = (j & 1) ? cosf(ang) : sinf(ang);
  pos[(size_t)i * DD + d] = val + level_embed[l * DD + d];
}

// ---------------- generic fp32 GEMM: C = (A+P?)(MxK) @ W(KxN) + bias (+R) (opt relu) ----
#define BM 128
#define BN 128
#define BK 16
__global__ __launch_bounds__(256) void gemm_kernel(
    const float* __restrict__ A, const float* __restrict__ P,
    const float* __restrict__ Wt,
    const float* __restrict__ bias, const float* __restrict__ R,
    float* __restrict__ C, int M, int N, int K, int do_relu)
{
  __shared__ float As[BK][BM + 4];
  __shared__ float Ws[BK][BN + 4];
  const int t  = threadIdx.x;
  const int n0 = blockIdx.x * BN;
  const int m0 = blockIdx.y * BM;
  const int tm = t >> 4;
  const int tn = t & 15;
  const int ar = t >> 1;
  const int ak = (t & 1) * 8;
  const int prow = (m0 + ar) % LEN;
  const int wk = t >> 4;
  const int wn = (t & 15) * 4;

  float acc[2][2][4][4];
#pragma unroll
  for (int mc = 0; mc < 2; ++mc)
#pragma unroll
    for (int nc = 0; nc < 2; ++nc)
#pragma unroll
      for (int i = 0; i < 4; ++i)
#pragma unroll
        for (int j = 0; j < 4; ++j) acc[mc][nc][i][j] = 0.f;

  for (int k0 = 0; k0 < K; k0 += BK) {
    float4 a0 = *reinterpret_cast<const float4*>(&A[(size_t)(m0 + ar) * K + k0 + ak]);
    float4 a1 = *reinterpret_cast<const float4*>(&A[(size_t)(m0 + ar) * K + k0 + ak + 4]);
    if (P) {
      const float4 p0 = *reinterpret_cast<const float4*>(&P[(size_t)prow * K + k0 + ak]);
      const float4 p1 = *reinterpret_cast<const float4*>(&P[(size_t)prow * K + k0 + ak + 4]);
      a0.x += p0.x; a0.y += p0.y; a0.z += p0.z; a0.w += p0.w;
      a1.x += p1.x; a1.y += p1.y; a1.z += p1.z; a1.w += p1.w;
    }
    As[ak + 0][ar] = a0.x; As[ak + 1][ar] = a0.y; As[ak + 2][ar] = a0.z; As[ak + 3][ar] = a0.w;
    As[ak + 4][ar] = a1.x; As[ak + 5][ar] = a1.y; As[ak + 6][ar] = a1.z; As[ak + 7][ar] = a1.w;
#pragma unroll
    for (int cc = 0; cc < 2; ++cc) {
      const int nb = wn + cc * 64;
      const size_t gro = (size_t)(k0 + wk) * N + n0;
      if (n0 + nb + 3 < N) {
        const float4 wv = *reinterpret_cast<const float4*>(&Wt[gro + nb]);
        Ws[wk][nb + 0] = wv.x; Ws[wk][nb + 1] = wv.y; Ws[wk][nb + 2] = wv.z; Ws[wk][nb + 3] = wv.w;
      } else {
#pragma unroll
        for (int i = 0; i < 4; ++i)
          Ws[wk][nb + i] = (n0 + nb + i < N) ? Wt[gro + nb + i] : 0.f;
      }
    }
    __syncthreads();
#pragma unroll
    for (int k = 0; k < BK; ++k) {
      float a[8], b[8];
      const float4 av0 = *reinterpret_cast<const float4*>(&As[k][tm * 4]);
      const float4 av1 = *reinterpret_cast<const float4*>(&As[k][64 + tm * 4]);
      const float4 bv0 = *reinterpret_cast<const float4*>(&Ws[k][tn * 4]);
      const float4 bv1 = *reinterpret_cast<const float4*>(&Ws[k][64 + tn * 4]);
      a[0]=av0.x; a[1]=av0.y; a[2]=av0.z; a[3]=av0.w;
      a[4]=av1.x; a[5]=av1.y; a[6]=av1.z; a[7]=av1.w;
      b[0]=bv0.x; b[1]=bv0.y; b[2]=bv0.z; b[3]=bv0.w;
      b[4]=bv1.x; b[5]=bv1.y; b[6]=bv1.z; b[7]=bv1.w;
#pragma unroll
      for (int mc = 0; mc < 2; ++mc)
#pragma unroll
        for (int i = 0; i < 4; ++i)
#pragma unroll
          for (int nc = 0; nc < 2; ++nc)
#pragma unroll
            for (int j = 0; j < 4; ++j)
              acc[mc][nc][i][j] = fmaf(a[mc*4+i], b[nc*4+j], acc[mc][nc][i][j]);
    }
    __syncthreads();
  }

#pragma unroll
  for (int mc = 0; mc < 2; ++mc) {
#pragma unroll
    for (int i = 0; i < 4; ++i) {
      const int m = m0 + mc * 64 + tm * 4 + i;
#pragma unroll
      for (int nc = 0; nc < 2; ++nc) {
        const int nb = n0 + nc * 64 + tn * 4;
        if (nb < N) {
          const float4 bb = *reinterpret_cast<const float4*>(&bias[nb]);
          float4 c;
          c.x = acc[mc][nc][i][0] + bb.x;
          c.y = acc[mc][nc][i][1] + bb.y;
          c.z = acc[mc][nc][i][2] + bb.z;
          c.w = acc[mc][nc][i][3] + bb.w;
          if (R) {
            const float4 rr = *reinterpret_cast<const float4*>(&R[(size_t)m * N + nb]);
            c.x += rr.x; c.y += rr.y; c.z += rr.z; c.w += rr.w;
          }
          if (do_relu) {
            c.x = fmaxf(c.x, 0.f); c.y = fmaxf(c.y, 0.f);
            c.z = fmaxf(c.z, 0.f); c.w = fmaxf(c.w, 0.f);
          }
          *reinterpret_cast<float4*>(&C[(size_t)m * N + nb]) = c;
        }
      }
    }
  }
}

// ---------------- softmax over 12 (per b,i,h), in place ----------------
__global__ void softmax12_kernel(float* __restrict__ aw)
{
  const size_t t = (size_t)blockIdx.x * blockDim.x + threadIdx.x;
  if (t >= (size_t)MTOT * NHH) return;
  float* p = aw + t * 12;
  float v[12];
  float m = -1e30f;
#pragma unroll
  for (int j = 0; j < 12; ++j) { v[j] = p[j]; m = fmaxf(m, v[j]); }
  float s = 0.f;
#pragma unroll
  for (int j = 0; j < 12; ++j) { v[j] = expf(v[j] - m); s += v[j]; }
  const float inv = 1.0f / s;
#pragma unroll
  for (int j = 0; j < 12; ++j) p[j] = v[j] * inv;
}

// ---------------- multi-scale deformable sampling + attention-weighted sum -------------
__global__ __launch_bounds__(256) void msdeform_kernel(
    const float* __restrict__ value, const float* __restrict__ off,
    const float* __restrict__ aw, float* __restrict__ samp)
{
  const int grp = threadIdx.x >> 5;
  const int d   = threadIdx.x & 31;
  const size_t idx = (size_t)blockIdx.x * 8 + grp;
  const int h = (int)(idx % NHH);
  const size_t bi = idx / NHH;
  const int i = (int)(bi % LEN);
  const int b = (int)(bi / LEN);

  int Hq, Wq, p;
  if (i < 4096)      { Hq = 64; Wq = 64; p = i; }
  else if (i < 5120) { Hq = 32; Wq = 32; p = i - 4096; }
  else               { Hq = 16; Wq = 16; p = i - 5120; }
  const float rx = ((p % Wq) + 0.5f) / (float)Wq;
  const float ry = ((p / Wq) + 0.5f) / (float)Hq;

  const float* offp = off + idx * (NLL * NPP * 2);
  const float* awp  = aw  + idx * 12;

  const int Ls[3] = {0, 4096, 5120};
  const int Hs[3] = {64, 32, 16};
  float acc = 0.f;
#pragma unroll
  for (int l = 0; l < 3; ++l) {
    const int Wl = Hs[l], Hl = Hs[l];
    const int st = Ls[l];
#pragma unroll
    for (int pp = 0; pp < 4; ++pp) {
      const float ox = offp[(l*4 + pp)*2 + 0];
      const float oy = offp[(l*4 + pp)*2 + 1];
      const float a  = awp[l*4 + pp];
      const float gx = rx * Wl + ox - 0.5f;
      const float gy = ry * Hl + oy - 0.5f;
      const float x0 = floorf(gx), y0 = floorf(gy);
      const float wx = gx - x0, wy = gy - y0;
      const int ix = (int)x0, iy = (int)y0;
#pragma unroll
      for (int c = 0; c < 4; ++c) {
        const int cx = ix + (c & 1), cy = iy + (c >> 1);
        const float wgt = ((c & 1) ? wx : 1.f - wx) * ((c >> 1) ? wy : 1.f - wy);
        if (cx >= 0 && cx < Wl && cy >= 0 && cy < Hl && d < DHH) {
          const float vv = value[(((size_t)b * LEN + st + cy*Wl + cx) * NHH + h) * DHH + d];
          acc = fmaf(a * wgt, vv, acc);
        }
      }
    }
  }
  if (d < DHH)
    samp[((size_t)b * LEN + i) * DD + h * DHH + d] = acc;
}

// ---------------- out = LN(X (+Y)) rowwise over 240 ----------------
__global__ __launch_bounds__(256) void add_ln_kernel(
    const float* __restrict__ X, const float* __restrict__ Y,
    const float* __restrict__ g, const float* __restrict__ bet,
    float* __restrict__ out)
{
  const int lane = threadIdx.x & 63;
  const int row  = blockIdx.x * 4 + (threadIdx.x >> 6);
  float4 v = make_float4(0.f, 0.f, 0.f, 0.f);
  if (lane < 60) {
    v = *reinterpret_cast<const float4*>(X + (size_t)row * DD + lane*4);
    if (Y) {
      const float4 w = *reinterpret_cast<const float4*>(Y + (size_t)row * DD + lane*4);
      v.x += w.x; v.y += w.y; v.z += w.z; v.w += w.w;
    }
  }
  float s = v.x + v.y + v.z + v.w;
#pragma unroll
  for (int o = 32; o > 0; o >>= 1) s += __shfl_xor(s, o, 64);
  const float mean = s * (1.0f / 240.0f);
  float sq = 0.f;
  if (lane < 60) {
    const float a = v.x - mean, b2 = v.y - mean, c = v.z - mean, e = v.w - mean;
    sq = a*a + b2*b2 + c*c + e*e;
  }
#pragma unroll
  for (int o = 32; o > 0; o >>= 1) sq += __shfl_xor(sq, o, 64);
  const float var = sq * (1.0f / 240.0f);
  const float rs = rsqrtf(var + 1e-5f);
  if (lane < 60) {
    const float4 gg = *reinterpret_cast<const float4*>(g + lane*4);
    const float4 bb = *reinterpret_cast<const float4*>(bet + lane*4);
    float* orow = out + (size_t)row * DD + lane*4;
    orow[0] = (v.x - mean) * rs * gg.x + bb.x;
    orow[1] = (v.y - mean) * rs * gg.y + bb.y;
    orow[2] = (v.z - mean) * rs * gg.z + bb.z;
    orow[3] = (v.w - mean) * rs * gg.w + bb.w;
  }
}

// ---------------- scatter (B,LEN,240) -> (B,240,H,W) with LDS transpose ----------------
template<int HW>
__global__ void scatter_kernel(const float* __restrict__ src2, float* __restrict__ out,
                               int start, size_t out_off)
{
  __shared__ float tile[32][33];
  const int tx = threadIdx.x;
  const int ty = threadIdx.y;
#pragma unroll
  for (int r = 0; r < 4; ++r) {
    const int prow = ty + 8*r;
    const int gp = blockIdx.x * 32 + prow;
    const int b = gp / HW, pix = gp % HW;
    const int co = blockIdx.y * 32 + tx;
    if (co < DD)
      tile[prow][tx] = src2[((size_t)b * LEN + start + pix) * DD + co];
  }
  __syncthreads();
#pragma unroll
  for (int r = 0; r < 4; ++r) {
    const int crow = ty + 8*r;
    const int co = blockIdx.y * 32 + crow;
    if (co < DD) {
      const int gp = blockIdx.x * 32 + tx;
      const int b = gp / HW, pix = gp % HW;
      out[out_off + ((size_t)b * DD + co) * HW + pix] = tile[tx][crow];
    }
  }
}

extern "C" void kernel_launch(void* const* d_in, const int* in_sizes, int n_in,
                              void* d_out, int out_size, void* d_ws, size_t ws_size,
                              hipStream_t stream)
{
  (void)in_sizes; (void)n_in; (void)out_size; (void)ws_size;
  const float* x0  = (const float*)d_in[0];
  const float* x1  = (const float*)d_in[1];
  const float* x2  = (const float*)d_in[2];
  const float* x3  = (const float*)d_in[3];
  const float* x4  = (const float*)d_in[4];
  const float* p2w = (const float*)d_in[5];
  const float* p2g = (const float*)d_in[6];
  const float* p2b = (const float*)d_in[7];
  const float* p3w = (const float*)d_in[8];
  const float* p3g = (const float*)d_in[9];
  const float* p3b = (const float*)d_in[10];
  const float* p4w = (const float*)d_in[11];
  const float* p4g = (const float*)d_in[12];
  const float* p4b = (const float*)d_in[13];
  const float* lev = (const float*)d_in[14];
  const float* so_w = (const float*)d_in[15];
  const float* so_b = (const float*)d_in[16];
  const float* aw_w = (const float*)d_in[17];
  const float* aw_b = (const float*)d_in[18];
  const float* vp_w = (const float*)d_in[19];
  const float* vp_b = (const float*)d_in[20];
  const float* op_w = (const float*)d_in[21];
  const float* op_b = (const float*)d_in[22];
  const float* n1g = (const float*)d_in[23];
  const float* n1b = (const float*)d_in[24];
  const float* f1w = (const float*)d_in[25];
  const float* f1b = (const float*)d_in[26];
  const float* f2w = (const float*)d_in[27];
  const float* f2b = (const float*)d_in[28];
  const float* n2g = (const float*)d_in[29];
  const float* n2b = (const float*)d_in[30];

  float* ws = (float*)d_ws;
  float* src  = ws + 0;               // 10,321,920
  float* offb = ws + 10321920;        //  8,257,536 (conv: wt0/1/2; later off, then attn)
  float* awb  = ws + 18579456;        //  4,128,768
  float* val  = ws + 22708224;        // 10,321,920 (conv: xt0/1/2; later value, then f2)
  float* smp  = ws + 33030144;        // 10,321,920 (later mid)
  float* pos  = ws + 43352064;        //  1,290,240
  float* src1 = ws + 44642304;        // 10,321,920 (conv: partials; later src1)
  float* attn = offb;
  float* mid  = smp;
  float* f2   = val;
  float* fin  = src;
  float* outf = (float*)d_out;

  // conv scratch overlays (all consumed before their regions are re-used)
  float* wt0 = offb;                  // 276,480
  float* wt1 = offb + 276480;         // 552,960
  float* wt2 = offb + 829440;         // 1,105,920
  float* xt0 = val;                   // 4,194,304
  float* xt1 = val + 4194304;         // 2,097,152
  float* xt2 = val + 6291456;         //   524,288
  float* part1 = src1;                // 3 * 8192 * 240 = 5,898,240
  float* part2 = src1 + 5898240;      // 3 * 2048 * 240 = 1,474,560

  // passthrough copies
  hipMemcpyAsync(outf, x0, (size_t)33554432 * 4, hipMemcpyDeviceToDevice, stream);
  hipMemcpyAsync(outf + 33554432, x1, (size_t)8388608 * 4, hipMemcpyDeviceToDevice, stream);

  // ---- convs as implicit GEMM ----
  nchw_to_nhwc_kernel<128,4096><<<dim3(128, 4, 8), dim3(32, 8), 0, stream>>>(x2, xt0);
  nchw_to_nhwc_kernel<256,1024><<<dim3(32, 8, 8),  dim3(32, 8), 0, stream>>>(x3, xt1);
  nchw_to_nhwc_kernel<512,256> <<<dim3(8, 16, 8),  dim3(32, 8), 0, stream>>>(x4, xt2);
  wtrans_kernel<128><<<dim3(36, 8),  dim3(32, 8), 0, stream>>>(p2w, wt0);
  wtrans_kernel<256><<<dim3(72, 8),  dim3(32, 8), 0, stream>>>(p3w, wt1);
  wtrans_kernel<512><<<dim3(144, 8), dim3(32, 8), 0, stream>>>(p4w, wt2);

  conv_gemm128_kernel<128,64,64><<<dim3(2, 256), 256, 0, stream>>>(xt0, wt0, p2g, p2b, src, 0);
  conv_gemm64s_kernel<256,32,32><<<dim3(2, 128, 3), 256, 0, stream>>>(xt1, wt1, part1);
  conv_gemm64s_kernel<512,16,16><<<dim3(2, 32, 3),  256, 0, stream>>>(xt2, wt2, part2);
  reduce3_bn_relu_kernel<1024><<<1920, 256, 0, stream>>>(part1, p3g, p3b, src, 4096);
  reduce3_bn_relu_kernel<256> <<<480,  256, 0, stream>>>(part2, p4g, p4b, src, 5120);

  pos_kernel<<<LEN, 256, 0, stream>>>(lev, pos);

  // projections (off/aw read src+pos via fused P operand)
  gemm_kernel<<<dim3(2, 336), 256, 0, stream>>>(src, pos, so_w, so_b, nullptr, offb, MTOT, 192, 240, 0);
  gemm_kernel<<<dim3(1, 336), 256, 0, stream>>>(src, pos, aw_w, aw_b, nullptr, awb,  MTOT,  96, 240, 0);
  softmax12_kernel<<<1344, 256, 0, stream>>>(awb);
  gemm_kernel<<<dim3(2, 336), 256, 0, stream>>>(src, nullptr, vp_w, vp_b, nullptr, val, MTOT, 240, 240, 0);

  msdeform_kernel<<<43008, 256, 0, stream>>>(val, offb, awb, smp);

  // output projection + residual LN1
  gemm_kernel<<<dim3(2, 336), 256, 0, stream>>>(smp, nullptr, op_w, op_b, nullptr, attn, MTOT, 240, 240, 0);
  add_ln_kernel<<<10752, 256, 0, stream>>>(src, attn, n1g, n1b, src1);

  // FFN, 4 row-chunks to bound workspace
  for (int c = 0; c < 4; ++c) {
    const float* a = src1 + (size_t)c * 10752 * DD;
    gemm_kernel<<<dim3(8, 84), 256, 0, stream>>>(a,   nullptr, f1w, f1b, nullptr, mid, 10752, 960, 240, 1);
    gemm_kernel<<<dim3(2, 84), 256, 0, stream>>>(mid, nullptr, f2w, f2b, a, f2 + (size_t)c * 10752 * DD,
                                                 10752, 240, 960, 0);
  }
  add_ln_kernel<<<10752, 256, 0, stream>>>(f2, nullptr, n2g, n2b, fin);

  // scatter back to NCHW outputs
  scatter_kernel<4096><<<dim3(1024, 8), dim3(32, 8), 0, stream>>>(fin, outf, 0,    41943040u);
  scatter_kernel<1024><<<dim3(256, 8),  dim3(32, 8), 0, stream>>>(fin, outf, 4096, 49807360u);
  scatter_kernel<256> <<<dim3(64, 8),   dim3(32, 8), 0, stream>>>(fin, outf, 5120, 51773440u);
}